// Round 8
// baseline (7281.049 us; speedup 1.0000x reference)
//
#include <hip/hip_runtime.h>
#include <math.h>

// Problem dims
#define SLEN 256
#define BSZ  128
#define DIN  128
#define HSZ  512
#define HH2  1024
#define GG3  1536
#define OSZ  25

typedef _Float16 h8 __attribute__((ext_vector_type(8)));
typedef _Float16 h4v __attribute__((ext_vector_type(4)));
typedef float    f4 __attribute__((ext_vector_type(4)));

struct P_t {
  const float *x, *noise, *b_cin, *b1, *b2, *b3, *w4, *b4, *b_ih, *b_hh, *w_out, *b_out;
  _Float16 *WT1, *WT2, *WT3, *WTih, *WThh, *WTcin;       // row-major [N][K] (setup)
  _Float16 *FW1T, *FW1B, *FW2, *FW3, *FWih, *FWhh;       // fragment-major
  _Float16 *CIN, *Z1, *Z2, *HGRU16;
  float *LOGI, *C1, *D1, *CIH3, *G3;                     // CIH3/G3: [row][512][3] f32
  float *A1, *AIH3, *AHH3, *HF, *HGRUF, *NF, *PART;
  int *CNT, *DEAD;
  float *out;
};

__device__ __forceinline__ f4 mfma16(h8 a, h8 b, f4 c) {
  return __builtin_amdgcn_mfma_f32_16x16x32_f16(a, b, c, 0, 0, 0);
}

// ---- coherent (L3) ops: intrinsics only (compiler pipelines relaxed atomics) ----
__device__ __forceinline__ float ldc_f(const float* p) {
  return __hip_atomic_load(p, __ATOMIC_RELAXED, __HIP_MEMORY_SCOPE_AGENT);
}
__device__ __forceinline__ void stc_f(float* p, float v) {
  __hip_atomic_store(p, v, __ATOMIC_RELAXED, __HIP_MEMORY_SCOPE_AGENT);
}
__device__ __forceinline__ unsigned ldc_u(const unsigned* p) {
  return __hip_atomic_load(p, __ATOMIC_RELAXED, __HIP_MEMORY_SCOPE_AGENT);
}
__device__ __forceinline__ void stc_u(unsigned* p, unsigned v) {
  __hip_atomic_store(p, v, __ATOMIC_RELAXED, __HIP_MEMORY_SCOPE_AGENT);
}

// Per-rt counting barrier (R7-proven pattern). Bounded spin + global DEAD flag:
// failures are fast-wrong, never hangs. CNT is monotone across dispatches.
__device__ __forceinline__ void rtbar(int* cnt, int target, int* dead) {
  asm volatile("s_waitcnt vmcnt(0)" ::: "memory");   // drain my wave's coherent stores
  __syncthreads();                                   // whole block drained
  if (threadIdx.x == 0) {
    __hip_atomic_fetch_add(cnt, 1, __ATOMIC_RELAXED, __HIP_MEMORY_SCOPE_AGENT);
    int tries = 0;
    while (__hip_atomic_load(cnt, __ATOMIC_RELAXED, __HIP_MEMORY_SCOPE_AGENT) < target) {
      if (((++tries) & 63) == 0) {
        if (tries > (1 << 16) ||
            __hip_atomic_load(dead, __ATOMIC_RELAXED, __HIP_MEMORY_SCOPE_AGENT)) {
          __hip_atomic_store(dead, 1, __ATOMIC_RELAXED, __HIP_MEMORY_SCOPE_AGENT);
          break;
        }
      }
      __builtin_amdgcn_s_sleep(2);
    }
  }
  __syncthreads();
}

// ---------------- setup kernels (R7-proven) ----------------
__global__ __launch_bounds__(256) void transpose_cvt(const float* __restrict__ src,
    _Float16* __restrict__ dst, int K, int N) {
  __shared__ float tl[32][33];
  int nt = N >> 5;
  int bx = blockIdx.x % nt, by = blockIdx.x / nt;
  int n0 = bx << 5, k0 = by << 5;
  int tx = threadIdx.x & 31, ty = threadIdx.x >> 5;
#pragma unroll
  for (int i = 0; i < 4; ++i) {
    int r = ty + (i << 3);
    tl[r][tx] = src[(size_t)(k0 + r) * N + n0 + tx];
  }
  __syncthreads();
#pragma unroll
  for (int i = 0; i < 4; ++i) {
    int r = ty + (i << 3);
    dst[(size_t)(n0 + r) * K + k0 + tx] = (_Float16)tl[tx][r];
  }
}

__global__ __launch_bounds__(512) void fragpack2(const _Float16* __restrict__ src,
    _Float16* __restrict__ dst, int srcK, int kOff, int K) {
  int ct = blockIdx.x;
  int chunks = (K / 32) * 64;
  for (int idx = threadIdx.x; idx < chunks; idx += 512) {
    int i = idx >> 6, lane = idx & 63;
    int mlw = lane & 15, qw = lane >> 4;
    *(h8*)(dst + ((size_t)ct * (K / 32) + i) * 512 + (size_t)lane * 8) =
        *(const h8*)(src + ((size_t)ct * 16 + mlw) * srcK + kOff + i * 32 + qw * 8);
  }
}

__global__ __launch_bounds__(256) void cin_kernel(P_t P) {
  int tid = blockIdx.x * blockDim.x + threadIdx.x;
  if (tid < SLEN * BSZ) {
    float u = P.noise[tid];
    P.LOGI[tid] = logf(u) - log1pf(-u);
  }
  int gw = tid >> 6, lane = tid & 63;
  int nw = (gridDim.x * blockDim.x) >> 6;
  int ml = lane & 15, q = lane >> 4;
  const int MT = (SLEN * BSZ) / 16;
  for (int tt = gw; tt < MT * 8; tt += nw) {
    int mt = tt & (MT - 1), nt = tt / MT;
    int m0 = mt * 16, n0 = nt * 64;
    int m = m0 + ml, b = m & 127, s = m >> 7;
    const float* ap = P.x + ((size_t)b * SLEN + s) * DIN + q * 8;
    const _Float16* bp = P.WTcin + (size_t)(n0 + ml) * DIN + q * 8;
    f4 a0 = {0,0,0,0}, a1 = a0, a2 = a0, a3 = a0;
#pragma unroll
    for (int k = 0; k < DIN; k += 32) {
      f4 lo = *(const f4*)(ap + k);
      f4 hi = *(const f4*)(ap + k + 4);
      h8 av;
      av[0] = (_Float16)lo[0]; av[1] = (_Float16)lo[1];
      av[2] = (_Float16)lo[2]; av[3] = (_Float16)lo[3];
      av[4] = (_Float16)hi[0]; av[5] = (_Float16)hi[1];
      av[6] = (_Float16)hi[2]; av[7] = (_Float16)hi[3];
      a0 = mfma16(av, *(const h8*)(bp + k),            a0);
      a1 = mfma16(av, *(const h8*)(bp + 16*DIN + k),   a1);
      a2 = mfma16(av, *(const h8*)(bp + 32*DIN + k),   a2);
      a3 = mfma16(av, *(const h8*)(bp + 48*DIN + k),   a3);
    }
#pragma unroll
    for (int r = 0; r < 4; ++r) {
      int row = m0 + q * 4 + r;
      int c0 = n0 + ml;
      P.CIN[(size_t)row * HSZ + c0     ] = (_Float16)tanhf(a0[r] + P.b_cin[c0]);
      P.CIN[(size_t)row * HSZ + c0 + 16] = (_Float16)tanhf(a1[r] + P.b_cin[c0 + 16]);
      P.CIN[(size_t)row * HSZ + c0 + 32] = (_Float16)tanhf(a2[r] + P.b_cin[c0 + 32]);
      P.CIN[(size_t)row * HSZ + c0 + 48] = (_Float16)tanhf(a3[r] + P.b_cin[c0 + 48]);
    }
  }
}

__global__ __launch_bounds__(256) void init_kernel(P_t P) {
  int idx = blockIdx.x * 256 + threadIdx.x;                 // 65536 threads
  for (int i = idx; i < BSZ * HH2; i += 65536) P.A1[i] = 0.f;
  for (int i = idx; i < BSZ * HSZ * 3; i += 65536) { P.AIH3[i] = 0.f; P.AHH3[i] = 0.f; }
  if (idx < BSZ * HSZ) P.HF[idx] = 0.f;
  if (idx < 2 * BSZ) P.NF[idx] = 0.f;
  if (idx < 128) P.CNT[idx] = 0;
  if (idx == 0) P.DEAD[0] = 0;
}

// bootstrap: Z1(0) = relu(cin(0)@W1bot + b1); HGRU(0) from biases (c=-h=0).
__global__ __launch_bounds__(256) void boot_kernel(P_t P) {
  const int tid = threadIdx.x, lane = tid & 63, wv = tid >> 6;
  const int ml = lane & 15, q = lane >> 4;
  const int g = blockIdx.x * 4 + wv;                         // grid 128 -> g<512
  {
    int rt = g & 7, ct = g >> 3, m0 = rt << 4, col = (ct << 4) + ml;
    const _Float16* a0 = P.CIN + (size_t)(m0 + ml) * HSZ + q * 8;
    const _Float16* bp = P.FW1B + (size_t)ct * 16 * 512 + (size_t)lane * 8;
    f4 acc = {0.f, 0.f, 0.f, 0.f};
#pragma unroll
    for (int k = 0; k < 16; ++k)
      acc = mfma16(*(const h8*)(a0 + k * 32), *(const h8*)(bp + (size_t)k * 512), acc);
    float bia = P.b1[col];
#pragma unroll
    for (int j = 0; j < 4; ++j)
      P.Z1[(size_t)(m0 + q * 4 + j) * HH2 + col] = (_Float16)fmaxf(acc[j] + bia, 0.f);
  }
  int e = blockIdx.x * 512 + tid;
#pragma unroll
  for (int rep = 0; rep < 2; ++rep, e += 256) {
    int row = e >> 9, cc = e & 511;
    float rg = 1.f / (1.f + expf(-(P.b_ih[cc] + P.b_hh[cc])));
    float zg = 1.f / (1.f + expf(-(P.b_ih[cc + 512] + P.b_hh[cc + 512])));
    float ng = tanhf(P.b_ih[cc + 1024] + rg * P.b_hh[cc + 1024]);
    float v = (1.f - zg) * ng;
    P.HGRUF[(size_t)row * HSZ + cc] = v;
    P.HGRU16[(size_t)row * HSZ + cc] = (_Float16)v;
  }
}

// ---------------- single step node: 256 blocks x 512 thr (8 waves) ----------------
// rt = b>>5 owns rows [rt*16, rt*16+16); sub = b&31. Co-residency guaranteed:
// 256 blocks <= 256 CUs at worst-case 1 block/CU (33KB LDS, VGPR<=256 via bounds).
// P1: z2(t) [sub<8] || transforms G/C1/CIH/D1 [sub>=8]  -> sc(L3) outputs
// B1 (per-rt, 32 arrivals); P2: z3(t) from LDS-staged Z2 -> PART; prefetch P3 data
// B2; P3: alpha + A1/AIH/AHH recurrences + Z1(t+1) + fused gates -> HGRU(t+1)
__global__ __launch_bounds__(512, 2) void step_node(P_t P, int t) {
  const int tid = threadIdx.x;
  const int lane = tid & 63, wv = tid >> 6;
  const int ml = lane & 15, q = lane >> 4;
  const int b = blockIdx.x, rt = b >> 5, sub = b & 31;
  const int m0 = rt << 4;
  const int slot = sub * 8 + wv;
  __shared__ unsigned sZd[16 * 516];
  __shared__ float sAl[16], sNN[16];
  int* cnt  = P.CNT + rt * 16;
  int* dead = P.DEAD;

  // ---------------- P1 ----------------
  if (sub < 8) {
    // z2 tile ct = slot (in [0,64))
    int ct = slot, col = (ct << 4) + ml;
    const _Float16* a0 = P.Z1 + (size_t)(m0 + ml) * HH2 + q * 8;
    const _Float16* bp = P.FW2 + (size_t)ct * 32 * 512 + (size_t)lane * 8;
    f4 acc = {0.f, 0.f, 0.f, 0.f};
#pragma unroll
    for (int k = 0; k < 32; ++k)
      acc = mfma16(*(const h8*)(a0 + k * 32), *(const h8*)(bp + (size_t)k * 512), acc);
    float bia = P.b2[col];
#pragma unroll
    for (int j = 0; j < 4; ++j) {
      _Float16 hv = (_Float16)fmaxf(acc[j] + bia, 0.f);
      unsigned short mb = __builtin_bit_cast(unsigned short, hv);
      unsigned ob = (unsigned)__shfl_xor((int)mb, 1) & 0xffffu;
      if (!(ml & 1))
        stc_u((unsigned*)&P.Z2[(size_t)(m0 + q * 4 + j) * HH2 + col],
              (unsigned)mb | (ob << 16));
    }
  } else {
    int ts = slot - 64;                         // [0,192)
    for (int e = ts; e < 320; e += 192) {
      f4 acc = {0.f, 0.f, 0.f, 0.f};
      if (e < 96) {                             // G = HGRU16(t) @ Whh (interleaved out)
        int ct = e, col = (ct << 4) + ml;
        const _Float16* a0 = P.HGRU16 + (size_t)(m0 + ml) * HSZ + q * 8;
        const _Float16* bp = P.FWhh + (size_t)ct * 16 * 512 + (size_t)lane * 8;
#pragma unroll
        for (int k = 0; k < 16; ++k)
          acc = mfma16(*(const h8*)(a0 + k * 32), *(const h8*)(bp + (size_t)k * 512), acc);
        int gate = col >> 9, cc = col & 511;
#pragma unroll
        for (int j = 0; j < 4; ++j)
          stc_f(P.G3 + ((size_t)(m0 + q * 4 + j) * 512 + cc) * 3 + gate, acc[j]);
      } else if (e < 160) {                     // C1 = cin(t) @ W1top
        int ct = e - 96, col = (ct << 4) + ml;
        const _Float16* a0 = P.CIN + ((size_t)t * BSZ + m0 + ml) * HSZ + q * 8;
        const _Float16* bp = P.FW1T + (size_t)ct * 16 * 512 + (size_t)lane * 8;
#pragma unroll
        for (int k = 0; k < 16; ++k)
          acc = mfma16(*(const h8*)(a0 + k * 32), *(const h8*)(bp + (size_t)k * 512), acc);
#pragma unroll
        for (int j = 0; j < 4; ++j)
          stc_f(P.C1 + (size_t)(m0 + q * 4 + j) * HH2 + col, acc[j]);
      } else if (e < 256) {                     // CIH = cin(t) @ Wih (interleaved out)
        int ct = e - 160, col = (ct << 4) + ml;
        const _Float16* a0 = P.CIN + ((size_t)t * BSZ + m0 + ml) * HSZ + q * 8;
        const _Float16* bp = P.FWih + (size_t)ct * 16 * 512 + (size_t)lane * 8;
#pragma unroll
        for (int k = 0; k < 16; ++k)
          acc = mfma16(*(const h8*)(a0 + k * 32), *(const h8*)(bp + (size_t)k * 512), acc);
        int gate = col >> 9, cc = col & 511;
#pragma unroll
        for (int j = 0; j < 4; ++j)
          stc_f(P.CIH3 + ((size_t)(m0 + q * 4 + j) * 512 + cc) * 3 + gate, acc[j]);
      } else if (t + 1 < SLEN) {                // D1 = cin(t+1) @ W1bot
        int ct = e - 256, col = (ct << 4) + ml;
        const _Float16* a0 = P.CIN + ((size_t)(t + 1) * BSZ + m0 + ml) * HSZ + q * 8;
        const _Float16* bp = P.FW1B + (size_t)ct * 16 * 512 + (size_t)lane * 8;
#pragma unroll
        for (int k = 0; k < 16; ++k)
          acc = mfma16(*(const h8*)(a0 + k * 32), *(const h8*)(bp + (size_t)k * 512), acc);
#pragma unroll
        for (int j = 0; j < 4; ++j)
          stc_f(P.D1 + (size_t)(m0 + q * 4 + j) * HH2 + col, acc[j]);
      }
    }
  }
  rtbar(cnt, t * 64 + 32, dead);

  // ---------------- P2: prefetch P3 operands, z3 on sub<8 ----------------
  const int rA = tid >> 5, cA = (sub << 5) + (tid & 31);
  const size_t oA = (size_t)(m0 + rA) * HH2 + cA;
  float c1v = ldc_f(P.C1 + oA);
  float d1v = (t + 1 < SLEN) ? ldc_f(P.D1 + oA) : 0.f;
  float a1old = P.A1[oA];
  float b1v = P.b1[cA];
  const int r3 = tid >> 4, cc3 = (sub << 4) + (tid & 15);
  const size_t o3 = ((size_t)(m0 + r3) * 512 + cc3) * 3;
  const size_t oh = (size_t)(m0 + r3) * HSZ + cc3;
  float cih0 = 0, cih1 = 0, cih2 = 0, g0 = 0, g1 = 0, g2 = 0;
  float aih0 = 0, aih1 = 0, aih2 = 0, ahh0 = 0, ahh1 = 0, ahh2 = 0;
  float bi0 = 0, bi1 = 0, bi2 = 0, bh0 = 0, bh1 = 0, bh2 = 0;
  float hfold = 0, hgrold = 0;
  if (tid < 256) {
    cih0 = ldc_f(P.CIH3 + o3); cih1 = ldc_f(P.CIH3 + o3 + 1); cih2 = ldc_f(P.CIH3 + o3 + 2);
    g0 = ldc_f(P.G3 + o3); g1 = ldc_f(P.G3 + o3 + 1); g2 = ldc_f(P.G3 + o3 + 2);
    aih0 = P.AIH3[o3]; aih1 = P.AIH3[o3 + 1]; aih2 = P.AIH3[o3 + 2];
    ahh0 = P.AHH3[o3]; ahh1 = P.AHH3[o3 + 1]; ahh2 = P.AHH3[o3 + 2];
    bi0 = P.b_ih[cc3]; bi1 = P.b_ih[cc3 + 512]; bi2 = P.b_ih[cc3 + 1024];
    bh0 = P.b_hh[cc3]; bh1 = P.b_hh[cc3 + 512]; bh2 = P.b_hh[cc3 + 1024];
    hfold = P.HF[oh]; hgrold = P.HGRUF[oh];
  }
  if (sub < 8) {
    // stage Z2 rows [m0,m0+16) into LDS via pipelined coherent dword loads
    unsigned vb[16];
    const unsigned* z2d = (const unsigned*)P.Z2 + (size_t)m0 * 512;
#pragma unroll
    for (int j = 0; j < 16; ++j) vb[j] = ldc_u(z2d + (size_t)j * 512 + tid);
#pragma unroll
    for (int j = 0; j < 16; ++j) sZd[j * 516 + tid] = vb[j];
    __syncthreads();
    int ct = slot, col = (ct << 4) + ml;
    const _Float16* a0 = (const _Float16*)sZd + ml * 1032 + q * 8;
    const _Float16* bp = P.FW3 + (size_t)ct * 32 * 512 + (size_t)lane * 8;
    f4 acc = {0.f, 0.f, 0.f, 0.f};
#pragma unroll
    for (int k = 0; k < 32; ++k)
      acc = mfma16(*(const h8*)(a0 + k * 32), *(const h8*)(bp + (size_t)k * 512), acc);
    float bia = P.b3[col], w4v = P.w4[col];
#pragma unroll
    for (int j = 0; j < 4; ++j) {
      float v = fmaxf(acc[j] + bia, 0.f) * w4v;
      v += __shfl_xor(v, 1); v += __shfl_xor(v, 2);
      v += __shfl_xor(v, 4); v += __shfl_xor(v, 8);
      if (ml == 0) stc_f(P.PART + (size_t)ct * BSZ + m0 + q * 4 + j, v);
    }
  }
  rtbar(cnt, t * 64 + 64, dead);

  // ---------------- P3 ----------------
  if (wv == 0) {
    int r = lane & 15, pq = lane >> 4;
    int row = m0 + r;
    float v = 0.f;
#pragma unroll
    for (int k = 0; k < 16; ++k)
      v += ldc_f(P.PART + (size_t)(pq * 16 + k) * BSZ + row);
    v += __shfl_xor(v, 16); v += __shfl_xor(v, 32);
    if (lane < 16) {
      float lg = (v + P.b4[0] + P.LOGI[(size_t)t * BSZ + row]) * 10.0f;
      float al = 1.f / (1.f + expf(-lg));
      float no = P.NF[((t + 1) & 1) * BSZ + row];
      float nn = no * (1.f - al) + 1.f;
      sAl[r] = al; sNN[r] = nn;
      if (sub == 0) P.NF[(t & 1) * BSZ + row] = nn;
    }
  }
  __syncthreads();
  {
    float al = sAl[rA], om = 1.f - al, rin = 1.f / sNN[rA];
    float a = om * a1old + c1v;
    P.A1[oA] = a;
    if (t + 1 < SLEN)
      P.Z1[oA] = (_Float16)fmaxf(a * rin + d1v + b1v, 0.f);
  }
  if (tid < 256) {
    float al = sAl[r3], om = 1.f - al, rin = 1.f / sNN[r3];
    float air = om * aih0 + cih0, aiz = om * aih1 + cih1, ain = om * aih2 + cih2;
    P.AIH3[o3] = air; P.AIH3[o3 + 1] = aiz; P.AIH3[o3 + 2] = ain;
    float ahr = om * ahh0 + al * g0, ahz = om * ahh1 + al * g1, ahn = om * ahh2 + al * g2;
    P.AHH3[o3] = ahr; P.AHH3[o3 + 1] = ahz; P.AHH3[o3 + 2] = ahn;
    float gxr = air * rin + bi0, gxz = aiz * rin + bi1, gxn = ain * rin + bi2;
    float ghr = ahr + bh0, ghz = ahz + bh1, ghn = ahn + bh2;
    float rg = 1.f / (1.f + expf(-(gxr + ghr)));
    float zg = 1.f / (1.f + expf(-(gxz + ghz)));
    float ng = tanhf(gxn + rg * ghn);
    float hnew = om * hfold + al * hgrold;          // h(t)
    P.HF[oh] = hnew;
    float hg1 = (1.f - zg) * ng + zg * hnew;        // HGRU(t+1)
    P.HGRUF[oh] = hg1;
    P.HGRU16[oh] = (_Float16)hg1;
  }
}

// ---------------- final: out = HGRU(256) @ w_out + b_out ----------------
__global__ __launch_bounds__(256) void final_out(P_t P) {
  __shared__ float hf[512];
  const int r = blockIdx.x, tid = threadIdx.x;
  const int lane = tid & 63, wv = tid >> 6;
  for (int e = tid; e < 512; e += 256) hf[e] = P.HGRUF[(size_t)r * HSZ + e];
  __syncthreads();
  for (int c = wv; c < OSZ; c += 4) {
    float v = 0.f;
#pragma unroll
    for (int j = 0; j < 8; ++j)
      v += hf[lane + 64 * j] * P.w_out[(size_t)(lane + 64 * j) * OSZ + c];
    for (int off = 32; off > 0; off >>= 1) v += __shfl_xor(v, off);
    if (lane == 0) P.out[r * OSZ + c] = v + P.b_out[c];
  }
}

// ---------------- host ----------------
extern "C" void kernel_launch(void* const* d_in, const int* in_sizes, int n_in,
                              void* d_out, int out_size, void* d_ws, size_t ws_size,
                              hipStream_t stream) {
  const float* x     = (const float*)d_in[0];
  const float* noise = (const float*)d_in[1];
  const float* w_cin = (const float*)d_in[2];
  const float* b_cin = (const float*)d_in[3];
  const float* w1    = (const float*)d_in[4];
  const float* b1    = (const float*)d_in[5];
  const float* w2    = (const float*)d_in[6];
  const float* b2    = (const float*)d_in[7];
  const float* w3    = (const float*)d_in[8];
  const float* b3    = (const float*)d_in[9];
  const float* w4    = (const float*)d_in[10];
  const float* b4    = (const float*)d_in[11];
  const float* w_ih  = (const float*)d_in[12];
  const float* b_ih  = (const float*)d_in[13];
  const float* w_hh  = (const float*)d_in[14];
  const float* b_hh  = (const float*)d_in[15];
  const float* w_out = (const float*)d_in[16];
  const float* b_out = (const float*)d_in[17];

  char* ws = (char*)d_ws;
  size_t off = 0;
  auto alloc = [&](size_t bytes) -> void* {
    void* p = ws + off;
    off = (off + bytes + 255) & ~(size_t)255;
    return p;
  };

  P_t P;
  P.x = x; P.noise = noise; P.b_cin = b_cin; P.b1 = b1; P.b2 = b2; P.b3 = b3;
  P.w4 = w4; P.b4 = b4; P.b_ih = b_ih; P.b_hh = b_hh; P.w_out = w_out; P.b_out = b_out;
  P.WT1    = (_Float16*)alloc((size_t)HH2 * HH2 * 2);
  P.WT2    = (_Float16*)alloc((size_t)HH2 * HH2 * 2);
  P.WT3    = (_Float16*)alloc((size_t)HH2 * HH2 * 2);
  P.WTih   = (_Float16*)alloc((size_t)GG3 * HSZ * 2);
  P.WThh   = (_Float16*)alloc((size_t)GG3 * HSZ * 2);
  P.WTcin  = (_Float16*)alloc((size_t)HSZ * DIN * 2);
  P.FW1T   = (_Float16*)alloc((size_t)HH2 * 512 * 2);
  P.FW1B   = (_Float16*)alloc((size_t)HH2 * 512 * 2);
  P.FW2    = (_Float16*)alloc((size_t)HH2 * HH2 * 2);
  P.FW3    = (_Float16*)alloc((size_t)HH2 * HH2 * 2);
  P.FWih   = (_Float16*)alloc((size_t)GG3 * HSZ * 2);
  P.FWhh   = (_Float16*)alloc((size_t)GG3 * HSZ * 2);
  P.CIN    = (_Float16*)alloc((size_t)SLEN * BSZ * HSZ * 2);
  P.Z1     = (_Float16*)alloc((size_t)BSZ * HH2 * 2);
  P.Z2     = (_Float16*)alloc((size_t)BSZ * HH2 * 2);
  P.HGRU16 = (_Float16*)alloc((size_t)BSZ * HSZ * 2);
  P.LOGI   = (float*)alloc((size_t)SLEN * BSZ * 4);
  P.C1     = (float*)alloc((size_t)BSZ * HH2 * 4);
  P.D1     = (float*)alloc((size_t)BSZ * HH2 * 4);
  P.CIH3   = (float*)alloc((size_t)BSZ * HSZ * 3 * 4);
  P.G3     = (float*)alloc((size_t)BSZ * HSZ * 3 * 4);
  P.A1     = (float*)alloc((size_t)BSZ * HH2 * 4);
  P.AIH3   = (float*)alloc((size_t)BSZ * HSZ * 3 * 4);
  P.AHH3   = (float*)alloc((size_t)BSZ * HSZ * 3 * 4);
  P.HF     = (float*)alloc((size_t)BSZ * HSZ * 4);
  P.HGRUF  = (float*)alloc((size_t)BSZ * HSZ * 4);
  P.NF     = (float*)alloc((size_t)2 * BSZ * 4);
  P.PART   = (float*)alloc((size_t)64 * BSZ * 4);
  P.CNT    = (int*)alloc(128 * 4);
  P.DEAD   = (int*)alloc(64 * 4);
  P.out    = (float*)d_out;

  transpose_cvt<<<(HH2/32)*(HH2/32), 256, 0, stream>>>(w1, P.WT1, HH2, HH2);
  transpose_cvt<<<(HH2/32)*(HH2/32), 256, 0, stream>>>(w2, P.WT2, HH2, HH2);
  transpose_cvt<<<(HH2/32)*(HH2/32), 256, 0, stream>>>(w3, P.WT3, HH2, HH2);
  transpose_cvt<<<(GG3/32)*(HSZ/32), 256, 0, stream>>>(w_ih, P.WTih, HSZ, GG3);
  transpose_cvt<<<(GG3/32)*(HSZ/32), 256, 0, stream>>>(w_hh, P.WThh, HSZ, GG3);
  transpose_cvt<<<(HSZ/32)*(DIN/32), 256, 0, stream>>>(w_cin, P.WTcin, DIN, HSZ);
  fragpack2<<<HH2/16, 512, 0, stream>>>(P.WT1, P.FW1T, HH2, 0, 512);
  fragpack2<<<HH2/16, 512, 0, stream>>>(P.WT1, P.FW1B, HH2, 512, 512);
  fragpack2<<<HH2/16, 512, 0, stream>>>(P.WT2, P.FW2, HH2, 0, HH2);
  fragpack2<<<HH2/16, 512, 0, stream>>>(P.WT3, P.FW3, HH2, 0, HH2);
  fragpack2<<<GG3/16, 512, 0, stream>>>(P.WTih, P.FWih, HSZ, 0, HSZ);
  fragpack2<<<GG3/16, 512, 0, stream>>>(P.WThh, P.FWhh, HSZ, 0, HSZ);

  cin_kernel<<<1024, 256, 0, stream>>>(P);
  init_kernel<<<256, 256, 0, stream>>>(P);
  boot_kernel<<<128, 256, 0, stream>>>(P);

  for (int t = 0; t < SLEN; ++t)
    step_node<<<256, 512, 0, stream>>>(P, t);
  final_out<<<BSZ, 256, 0, stream>>>(P);
}

// Round 9
// 7117.147 us; speedup vs baseline: 1.0230x; 1.0230x over previous
//
#include <hip/hip_runtime.h>
#include <math.h>

// Problem dims
#define SLEN 256
#define BSZ  128
#define DIN  128
#define HSZ  512
#define HH2  1024
#define GG3  1536
#define OSZ  25

typedef _Float16 h8 __attribute__((ext_vector_type(8)));
typedef _Float16 h4v __attribute__((ext_vector_type(4)));
typedef float    f4 __attribute__((ext_vector_type(4)));

struct P_t {
  const float *x, *noise, *b_cin, *b1, *b2, *b3, *w4, *b4, *b_ih, *b_hh, *w_out, *b_out;
  _Float16 *WT1, *WT2, *WT3, *WTih, *WThh, *WTcin;       // row-major [N][K] (setup)
  _Float16 *FW1T, *FW1B, *FW2, *FW3, *FWih, *FWhh;       // fragment-major
  _Float16 *CIN, *Z1, *Z2, *HGRU16;
  float *LOGI, *C1, *D1, *CIH3, *G3;                     // CIH3/G3: [row][512][3] f32
  float *A1, *AIH3, *AHH3, *HF, *HGRUF, *NF, *PART;
  int *CNT, *DEAD;
  float *out;
};

__device__ __forceinline__ f4 mfma16(h8 a, h8 b, f4 c) {
  return __builtin_amdgcn_mfma_f32_16x16x32_f16(a, b, c, 0, 0, 0);
}

// ---- L3-coherent ops: ONLY for in-kernel cross-block data (PART, CNT, DEAD) ----
__device__ __forceinline__ float ldc_f(const float* p) {
  return __hip_atomic_load(p, __ATOMIC_RELAXED, __HIP_MEMORY_SCOPE_AGENT);
}
__device__ __forceinline__ void stc_f(float* p, float v) {
  __hip_atomic_store(p, v, __ATOMIC_RELAXED, __HIP_MEMORY_SCOPE_AGENT);
}

// Per-rt counting barrier (R7-proven). Bounded spin + DEAD flag: fail-fast, no hang.
__device__ __forceinline__ void rtbar(int* cnt, int target, int* dead) {
  asm volatile("s_waitcnt vmcnt(0)" ::: "memory");
  __syncthreads();
  if (threadIdx.x == 0) {
    __hip_atomic_fetch_add(cnt, 1, __ATOMIC_RELAXED, __HIP_MEMORY_SCOPE_AGENT);
    int tries = 0;
    while (__hip_atomic_load(cnt, __ATOMIC_RELAXED, __HIP_MEMORY_SCOPE_AGENT) < target) {
      if (((++tries) & 63) == 0) {
        if (tries > (1 << 16) ||
            __hip_atomic_load(dead, __ATOMIC_RELAXED, __HIP_MEMORY_SCOPE_AGENT)) {
          __hip_atomic_store(dead, 1, __ATOMIC_RELAXED, __HIP_MEMORY_SCOPE_AGENT);
          break;
        }
      }
      __builtin_amdgcn_s_sleep(2);
    }
  }
  __syncthreads();
}

// ---------------- setup kernels (proven) ----------------
__global__ __launch_bounds__(256) void transpose_cvt(const float* __restrict__ src,
    _Float16* __restrict__ dst, int K, int N) {
  __shared__ float tl[32][33];
  int nt = N >> 5;
  int bx = blockIdx.x % nt, by = blockIdx.x / nt;
  int n0 = bx << 5, k0 = by << 5;
  int tx = threadIdx.x & 31, ty = threadIdx.x >> 5;
#pragma unroll
  for (int i = 0; i < 4; ++i) {
    int r = ty + (i << 3);
    tl[r][tx] = src[(size_t)(k0 + r) * N + n0 + tx];
  }
  __syncthreads();
#pragma unroll
  for (int i = 0; i < 4; ++i) {
    int r = ty + (i << 3);
    dst[(size_t)(n0 + r) * K + k0 + tx] = (_Float16)tl[tx][r];
  }
}

__global__ __launch_bounds__(512) void fragpack2(const _Float16* __restrict__ src,
    _Float16* __restrict__ dst, int srcK, int kOff, int K) {
  int ct = blockIdx.x;
  int chunks = (K / 32) * 64;
  for (int idx = threadIdx.x; idx < chunks; idx += 512) {
    int i = idx >> 6, lane = idx & 63;
    int mlw = lane & 15, qw = lane >> 4;
    *(h8*)(dst + ((size_t)ct * (K / 32) + i) * 512 + (size_t)lane * 8) =
        *(const h8*)(src + ((size_t)ct * 16 + mlw) * srcK + kOff + i * 32 + qw * 8);
  }
}

__global__ __launch_bounds__(256) void cin_kernel(P_t P) {
  int tid = blockIdx.x * blockDim.x + threadIdx.x;
  if (tid < SLEN * BSZ) {
    float u = P.noise[tid];
    P.LOGI[tid] = logf(u) - log1pf(-u);
  }
  int gw = tid >> 6, lane = tid & 63;
  int nw = (gridDim.x * blockDim.x) >> 6;
  int ml = lane & 15, q = lane >> 4;
  const int MT = (SLEN * BSZ) / 16;
  for (int tt = gw; tt < MT * 8; tt += nw) {
    int mt = tt & (MT - 1), nt = tt / MT;
    int m0 = mt * 16, n0 = nt * 64;
    int m = m0 + ml, b = m & 127, s = m >> 7;
    const float* ap = P.x + ((size_t)b * SLEN + s) * DIN + q * 8;
    const _Float16* bp = P.WTcin + (size_t)(n0 + ml) * DIN + q * 8;
    f4 a0 = {0,0,0,0}, a1 = a0, a2 = a0, a3 = a0;
#pragma unroll
    for (int k = 0; k < DIN; k += 32) {
      f4 lo = *(const f4*)(ap + k);
      f4 hi = *(const f4*)(ap + k + 4);
      h8 av;
      av[0] = (_Float16)lo[0]; av[1] = (_Float16)lo[1];
      av[2] = (_Float16)lo[2]; av[3] = (_Float16)lo[3];
      av[4] = (_Float16)hi[0]; av[5] = (_Float16)hi[1];
      av[6] = (_Float16)hi[2]; av[7] = (_Float16)hi[3];
      a0 = mfma16(av, *(const h8*)(bp + k),            a0);
      a1 = mfma16(av, *(const h8*)(bp + 16*DIN + k),   a1);
      a2 = mfma16(av, *(const h8*)(bp + 32*DIN + k),   a2);
      a3 = mfma16(av, *(const h8*)(bp + 48*DIN + k),   a3);
    }
#pragma unroll
    for (int r = 0; r < 4; ++r) {
      int row = m0 + q * 4 + r;
      int c0 = n0 + ml;
      P.CIN[(size_t)row * HSZ + c0     ] = (_Float16)tanhf(a0[r] + P.b_cin[c0]);
      P.CIN[(size_t)row * HSZ + c0 + 16] = (_Float16)tanhf(a1[r] + P.b_cin[c0 + 16]);
      P.CIN[(size_t)row * HSZ + c0 + 32] = (_Float16)tanhf(a2[r] + P.b_cin[c0 + 32]);
      P.CIN[(size_t)row * HSZ + c0 + 48] = (_Float16)tanhf(a3[r] + P.b_cin[c0 + 48]);
    }
  }
}

__global__ __launch_bounds__(256) void init_kernel(P_t P) {
  int idx = blockIdx.x * 256 + threadIdx.x;                 // 65536 threads
  for (int i = idx; i < BSZ * HH2; i += 65536) P.A1[i] = 0.f;
  for (int i = idx; i < BSZ * HSZ * 3; i += 65536) { P.AIH3[i] = 0.f; P.AHH3[i] = 0.f; }
  if (idx < BSZ * HSZ) P.HF[idx] = 0.f;
  if (idx < 2 * BSZ) P.NF[idx] = 0.f;
  if (idx < 128) P.CNT[idx] = 0;
  if (idx == 0) P.DEAD[0] = 0;
}

// bootstrap: Z1(0) = relu(cin(0)@W1bot + b1); HGRU(0) from biases (c=h=0).
__global__ __launch_bounds__(256) void boot_kernel(P_t P) {
  const int tid = threadIdx.x, lane = tid & 63, wv = tid >> 6;
  const int ml = lane & 15, q = lane >> 4;
  const int g = blockIdx.x * 4 + wv;                         // grid 128 -> g<512
  {
    int rt = g & 7, ct = g >> 3, m0 = rt << 4, col = (ct << 4) + ml;
    const _Float16* a0 = P.CIN + (size_t)(m0 + ml) * HSZ + q * 8;
    const _Float16* bp = P.FW1B + (size_t)ct * 16 * 512 + (size_t)lane * 8;
    f4 acc = {0.f, 0.f, 0.f, 0.f};
#pragma unroll
    for (int k = 0; k < 16; ++k)
      acc = mfma16(*(const h8*)(a0 + k * 32), *(const h8*)(bp + (size_t)k * 512), acc);
    float bia = P.b1[col];
#pragma unroll
    for (int j = 0; j < 4; ++j)
      P.Z1[(size_t)(m0 + q * 4 + j) * HH2 + col] = (_Float16)fmaxf(acc[j] + bia, 0.f);
  }
  int e = blockIdx.x * 512 + tid;
#pragma unroll
  for (int rep = 0; rep < 2; ++rep, e += 256) {
    int row = e >> 9, cc = e & 511;
    float rg = 1.f / (1.f + expf(-(P.b_ih[cc] + P.b_hh[cc])));
    float zg = 1.f / (1.f + expf(-(P.b_ih[cc + 512] + P.b_hh[cc + 512])));
    float ng = tanhf(P.b_ih[cc + 1024] + rg * P.b_hh[cc + 1024]);
    float v = (1.f - zg) * ng;
    P.HGRUF[(size_t)row * HSZ + cc] = v;
    P.HGRU16[(size_t)row * HSZ + cc] = (_Float16)v;
  }
}

// ---------------- node_a: independent GEMM bundle, 4-wide ILP tiles ----------------
// 768 one-wave blocks. Each wave computes a 16x64 output group (4 accumulators, one
// shared A-fragment, 4 independent B-streams -> 4x outstanding loads, A-traffic /4).
// Tiles: [0,128) z2 | [128,320) G=HGRU16@Whh | [320,448) C1 | [448,640) CIH | [640,768) D1
// All I/O on the normal cached path (dispatch-boundary release/acquire = coherence).
__global__ __launch_bounds__(64) void node_a(P_t P, int t) {
  const int lane = threadIdx.x;
  const int ml = lane & 15, q = lane >> 4;
  const int g = blockIdx.x;
  f4 ac0 = {0.f,0.f,0.f,0.f}, ac1 = ac0, ac2 = ac0, ac3 = ac0;
  if (g < 128) {                        // z2(t), K=1024
    int rt = g & 7, c64 = g >> 3, m0 = rt << 4;
    const _Float16* ap = P.Z1 + (size_t)(m0 + ml) * HH2 + q * 8;
    const _Float16* bp = P.FW2 + (size_t)c64 * 4 * 16384 + (size_t)lane * 8;
#pragma unroll
    for (int k = 0; k < 32; ++k) {
      h8 av = *(const h8*)(ap + k * 32);
      ac0 = mfma16(av, *(const h8*)(bp + (size_t)k * 512        ), ac0);
      ac1 = mfma16(av, *(const h8*)(bp + (size_t)k * 512 + 16384), ac1);
      ac2 = mfma16(av, *(const h8*)(bp + (size_t)k * 512 + 32768), ac2);
      ac3 = mfma16(av, *(const h8*)(bp + (size_t)k * 512 + 49152), ac3);
    }
    int cb = c64 * 64 + ml;
    float b0 = P.b2[cb], b1 = P.b2[cb+16], b2 = P.b2[cb+32], b3 = P.b2[cb+48];
#pragma unroll
    for (int j = 0; j < 4; ++j) {
      size_t ro = (size_t)(m0 + q*4 + j) * HH2 + cb;
      P.Z2[ro     ] = (_Float16)fmaxf(ac0[j] + b0, 0.f);
      P.Z2[ro + 16] = (_Float16)fmaxf(ac1[j] + b1, 0.f);
      P.Z2[ro + 32] = (_Float16)fmaxf(ac2[j] + b2, 0.f);
      P.Z2[ro + 48] = (_Float16)fmaxf(ac3[j] + b3, 0.f);
    }
  } else if (g < 320) {                 // G(t) = HGRU16(t) @ Whh, K=512
    int u = g - 128; int rt = u & 7, c64 = u >> 3, m0 = rt << 4;
    const _Float16* ap = P.HGRU16 + (size_t)(m0 + ml) * HSZ + q * 8;
    const _Float16* bp = P.FWhh + (size_t)c64 * 4 * 8192 + (size_t)lane * 8;
#pragma unroll
    for (int k = 0; k < 16; ++k) {
      h8 av = *(const h8*)(ap + k * 32);
      ac0 = mfma16(av, *(const h8*)(bp + (size_t)k * 512        ), ac0);
      ac1 = mfma16(av, *(const h8*)(bp + (size_t)k * 512 +  8192), ac1);
      ac2 = mfma16(av, *(const h8*)(bp + (size_t)k * 512 + 16384), ac2);
      ac3 = mfma16(av, *(const h8*)(bp + (size_t)k * 512 + 24576), ac3);
    }
    int base = c64 * 64;
#pragma unroll
    for (int uu = 0; uu < 4; ++uu) {
      f4 a = uu==0?ac0:uu==1?ac1:uu==2?ac2:ac3;
      int colq = base + uu * 16;
      int gate = colq >> 9, cc = (colq & 511) + ml;
#pragma unroll
      for (int j = 0; j < 4; ++j)
        P.G3[((size_t)(m0 + q*4 + j) * 512 + cc) * 3 + gate] = a[j];
    }
  } else if (g < 448) {                 // C1(t) = cin(t) @ W1top, K=512
    int u = g - 320; int rt = u & 7, c64 = u >> 3, m0 = rt << 4;
    const _Float16* ap = P.CIN + ((size_t)t * BSZ + m0 + ml) * HSZ + q * 8;
    const _Float16* bp = P.FW1T + (size_t)c64 * 4 * 8192 + (size_t)lane * 8;
#pragma unroll
    for (int k = 0; k < 16; ++k) {
      h8 av = *(const h8*)(ap + k * 32);
      ac0 = mfma16(av, *(const h8*)(bp + (size_t)k * 512        ), ac0);
      ac1 = mfma16(av, *(const h8*)(bp + (size_t)k * 512 +  8192), ac1);
      ac2 = mfma16(av, *(const h8*)(bp + (size_t)k * 512 + 16384), ac2);
      ac3 = mfma16(av, *(const h8*)(bp + (size_t)k * 512 + 24576), ac3);
    }
    int cb = c64 * 64 + ml;
#pragma unroll
    for (int j = 0; j < 4; ++j) {
      size_t ro = (size_t)(m0 + q*4 + j) * HH2 + cb;
      P.C1[ro] = ac0[j]; P.C1[ro+16] = ac1[j]; P.C1[ro+32] = ac2[j]; P.C1[ro+48] = ac3[j];
    }
  } else if (g < 640) {                 // CIH(t) = cin(t) @ Wih, K=512
    int u = g - 448; int rt = u & 7, c64 = u >> 3, m0 = rt << 4;
    const _Float16* ap = P.CIN + ((size_t)t * BSZ + m0 + ml) * HSZ + q * 8;
    const _Float16* bp = P.FWih + (size_t)c64 * 4 * 8192 + (size_t)lane * 8;
#pragma unroll
    for (int k = 0; k < 16; ++k) {
      h8 av = *(const h8*)(ap + k * 32);
      ac0 = mfma16(av, *(const h8*)(bp + (size_t)k * 512        ), ac0);
      ac1 = mfma16(av, *(const h8*)(bp + (size_t)k * 512 +  8192), ac1);
      ac2 = mfma16(av, *(const h8*)(bp + (size_t)k * 512 + 16384), ac2);
      ac3 = mfma16(av, *(const h8*)(bp + (size_t)k * 512 + 24576), ac3);
    }
    int base = c64 * 64;
#pragma unroll
    for (int uu = 0; uu < 4; ++uu) {
      f4 a = uu==0?ac0:uu==1?ac1:uu==2?ac2:ac3;
      int colq = base + uu * 16;
      int gate = colq >> 9, cc = (colq & 511) + ml;
#pragma unroll
      for (int j = 0; j < 4; ++j)
        P.CIH3[((size_t)(m0 + q*4 + j) * 512 + cc) * 3 + gate] = a[j];
    }
  } else {                              // D1(t) = cin(t+1) @ W1bot, K=512
    if (t + 1 < SLEN) {
      int u = g - 640; int rt = u & 7, c64 = u >> 3, m0 = rt << 4;
      const _Float16* ap = P.CIN + ((size_t)(t + 1) * BSZ + m0 + ml) * HSZ + q * 8;
      const _Float16* bp = P.FW1B + (size_t)c64 * 4 * 8192 + (size_t)lane * 8;
#pragma unroll
      for (int k = 0; k < 16; ++k) {
        h8 av = *(const h8*)(ap + k * 32);
        ac0 = mfma16(av, *(const h8*)(bp + (size_t)k * 512        ), ac0);
        ac1 = mfma16(av, *(const h8*)(bp + (size_t)k * 512 +  8192), ac1);
        ac2 = mfma16(av, *(const h8*)(bp + (size_t)k * 512 + 16384), ac2);
        ac3 = mfma16(av, *(const h8*)(bp + (size_t)k * 512 + 24576), ac3);
      }
      int cb = c64 * 64 + ml;
#pragma unroll
      for (int j = 0; j < 4; ++j) {
        size_t ro = (size_t)(m0 + q*4 + j) * HH2 + cb;
        P.D1[ro] = ac0[j]; P.D1[ro+16] = ac1[j]; P.D1[ro+32] = ac2[j]; P.D1[ro+48] = ac3[j];
      }
    }
  }
}

// ---------------- node_b: z3 -> PART (L3) -> per-rt barrier -> tail ----------------
// 256 blocks x 256 thr (VGPR<=256 via bounds(256,2) -> no spills). rt=b>>5, sub=b&31.
// All blocks prefetch tail operands FIRST (prev-dispatch data, plain loads); subs 0-7
// run 2-wide z3 tiles concurrently -> tail-load latency hides under z3. PART crosses
// blocks in-kernel -> L3 path + rtbar (32 arrivals/rt). Tail split 32 ways.
__global__ __launch_bounds__(256, 2) void node_b(P_t P, int t) {
  const int tid = threadIdx.x;
  const int lane = tid & 63, wv = tid >> 6;
  const int ml = lane & 15, q = lane >> 4;
  const int b = blockIdx.x, rt = b >> 5, sub = b & 31;
  const int m0 = rt << 4;
  __shared__ float sAl[16], sNN[16];
  int* cnt  = P.CNT + rt * 16;
  int* dead = P.DEAD;

  // ---- prefetch tail operands (all prev-dispatch, plain cached loads) ----
  const int rA = tid >> 5;                       // 0..7  (rows rA and rA+8)
  const int cA = (sub << 5) + (tid & 31);        // 32 cols per sub
  const size_t oA0 = (size_t)(m0 + rA) * HH2 + cA;
  const size_t oA1 = (size_t)(m0 + rA + 8) * HH2 + cA;
  float a1o0 = P.A1[oA0], c1v0 = P.C1[oA0];
  float a1o1 = P.A1[oA1], c1v1 = P.C1[oA1];
  float d1v0 = 0.f, d1v1 = 0.f;
  if (t + 1 < SLEN) { d1v0 = P.D1[oA0]; d1v1 = P.D1[oA1]; }
  float b1v = P.b1[cA];
  const int r3 = tid >> 4, cc3 = (sub << 4) + (tid & 15);   // 16 gate-cols per sub
  const size_t o3 = ((size_t)(m0 + r3) * 512 + cc3) * 3;
  const size_t oh = (size_t)(m0 + r3) * HSZ + cc3;
  float cih0 = P.CIH3[o3], cih1 = P.CIH3[o3 + 1], cih2 = P.CIH3[o3 + 2];
  float g0 = P.G3[o3], g1 = P.G3[o3 + 1], g2 = P.G3[o3 + 2];
  float aih0 = P.AIH3[o3], aih1 = P.AIH3[o3 + 1], aih2 = P.AIH3[o3 + 2];
  float ahh0 = P.AHH3[o3], ahh1 = P.AHH3[o3 + 1], ahh2 = P.AHH3[o3 + 2];
  float bi0 = P.b_ih[cc3], bi1 = P.b_ih[cc3 + 512], bi2 = P.b_ih[cc3 + 1024];
  float bh0 = P.b_hh[cc3], bh1 = P.b_hh[cc3 + 512], bh2 = P.b_hh[cc3 + 1024];
  float hfold = P.HF[oh], hgrold = P.HGRUF[oh];

  // ---- z3(t) on subs 0..7: 2-wide tiles (16x32 per wave) ----
  if (sub < 8) {
    int c32 = sub * 4 + wv;                      // 0..31 col-group of 32
    const _Float16* ap = P.Z2 + (size_t)(m0 + ml) * HH2 + q * 8;
    const _Float16* bp = P.FW3 + (size_t)c32 * 2 * 16384 + (size_t)lane * 8;
    f4 ac0 = {0.f,0.f,0.f,0.f}, ac1 = ac0;
#pragma unroll
    for (int k = 0; k < 32; ++k) {
      h8 av = *(const h8*)(ap + k * 32);
      ac0 = mfma16(av, *(const h8*)(bp + (size_t)k * 512        ), ac0);
      ac1 = mfma16(av, *(const h8*)(bp + (size_t)k * 512 + 16384), ac1);
    }
#pragma unroll
    for (int uu = 0; uu < 2; ++uu) {
      f4 a = uu ? ac1 : ac0;
      int ct = c32 * 2 + uu, col = (ct << 4) + ml;
      float bia = P.b3[col], w4v = P.w4[col];
#pragma unroll
      for (int j = 0; j < 4; ++j) {
        float v = fmaxf(a[j] + bia, 0.f) * w4v;
        v += __shfl_xor(v, 1); v += __shfl_xor(v, 2);
        v += __shfl_xor(v, 4); v += __shfl_xor(v, 8);
        if (ml == 0) stc_f(P.PART + (size_t)ct * BSZ + m0 + q * 4 + j, v);
      }
    }
  }
  rtbar(cnt, 32 * (t + 1), dead);

  // ---- alpha(t), n(t) ----
  if (wv == 0) {
    int r = lane & 15, pq = lane >> 4;
    int row = m0 + r;
    float v = 0.f;
#pragma unroll
    for (int k = 0; k < 16; ++k)
      v += ldc_f(P.PART + (size_t)(pq * 16 + k) * BSZ + row);
    v += __shfl_xor(v, 16); v += __shfl_xor(v, 32);
    if (lane < 16) {
      float lg = (v + P.b4[0] + P.LOGI[(size_t)t * BSZ + row]) * 10.0f;
      float al = 1.f / (1.f + expf(-lg));
      float no = P.NF[((t + 1) & 1) * BSZ + row];
      float nn = no * (1.f - al) + 1.f;
      sAl[r] = al; sNN[r] = nn;
      if (sub == 0) P.NF[(t & 1) * BSZ + row] = nn;
    }
  }
  __syncthreads();

  // ---- A1 recurrence + Z1(t+1) (2 elems/thread) ----
  {
    float al0 = sAl[rA], om0 = 1.f - al0, ri0 = 1.f / sNN[rA];
    float a = om0 * a1o0 + c1v0;
    P.A1[oA0] = a;
    if (t + 1 < SLEN)
      P.Z1[oA0] = (_Float16)fmaxf(a * ri0 + d1v0 + b1v, 0.f);
    float al1 = sAl[rA + 8], om1 = 1.f - al1, ri1 = 1.f / sNN[rA + 8];
    float a2 = om1 * a1o1 + c1v1;
    P.A1[oA1] = a2;
    if (t + 1 < SLEN)
      P.Z1[oA1] = (_Float16)fmaxf(a2 * ri1 + d1v1 + b1v, 0.f);
  }

  // ---- AIH/AHH recurrences + fused gates -> h(t), HGRU(t+1) (1 triple/thread) ----
  {
    float al = sAl[r3], om = 1.f - al, rin = 1.f / sNN[r3];
    float air = om * aih0 + cih0, aiz = om * aih1 + cih1, ain = om * aih2 + cih2;
    P.AIH3[o3] = air; P.AIH3[o3 + 1] = aiz; P.AIH3[o3 + 2] = ain;
    float ahr = om * ahh0 + al * g0, ahz = om * ahh1 + al * g1, ahn = om * ahh2 + al * g2;
    P.AHH3[o3] = ahr; P.AHH3[o3 + 1] = ahz; P.AHH3[o3 + 2] = ahn;
    float gxr = air * rin + bi0, gxz = aiz * rin + bi1, gxn = ain * rin + bi2;
    float ghr = ahr + bh0, ghz = ahz + bh1, ghn = ahn + bh2;
    float rg = 1.f / (1.f + expf(-(gxr + ghr)));
    float zg = 1.f / (1.f + expf(-(gxz + ghz)));
    float ng = tanhf(gxn + rg * ghn);
    float hnew = om * hfold + al * hgrold;          // h(t)
    P.HF[oh] = hnew;
    float hg1 = (1.f - zg) * ng + zg * hnew;        // HGRU(t+1)
    P.HGRUF[oh] = hg1;
    P.HGRU16[oh] = (_Float16)hg1;
  }
}

// ---------------- final: out = HGRU(256) @ w_out + b_out ----------------
__global__ __launch_bounds__(256) void final_out(P_t P) {
  __shared__ float hf[512];
  const int r = blockIdx.x, tid = threadIdx.x;
  const int lane = tid & 63, wv = tid >> 6;
  for (int e = tid; e < 512; e += 256) hf[e] = P.HGRUF[(size_t)r * HSZ + e];
  __syncthreads();
  for (int c = wv; c < OSZ; c += 4) {
    float v = 0.f;
#pragma unroll
    for (int j = 0; j < 8; ++j)
      v += hf[lane + 64 * j] * P.w_out[(size_t)(lane + 64 * j) * OSZ + c];
    for (int off = 32; off > 0; off >>= 1) v += __shfl_xor(v, off);
    if (lane == 0) P.out[r * OSZ + c] = v + P.b_out[c];
  }
}

// ---------------- host ----------------
extern "C" void kernel_launch(void* const* d_in, const int* in_sizes, int n_in,
                              void* d_out, int out_size, void* d_ws, size_t ws_size,
                              hipStream_t stream) {
  const float* x     = (const float*)d_in[0];
  const float* noise = (const float*)d_in[1];
  const float* w_cin = (const float*)d_in[2];
  const float* b_cin = (const float*)d_in[3];
  const float* w1    = (const float*)d_in[4];
  const float* b1    = (const float*)d_in[5];
  const float* w2    = (const float*)d_in[6];
  const float* b2    = (const float*)d_in[7];
  const float* w3    = (const float*)d_in[8];
  const float* b3    = (const float*)d_in[9];
  const float* w4    = (const float*)d_in[10];
  const float* b4    = (const float*)d_in[11];
  const float* w_ih  = (const float*)d_in[12];
  const float* b_ih  = (const float*)d_in[13];
  const float* w_hh  = (const float*)d_in[14];
  const float* b_hh  = (const float*)d_in[15];
  const float* w_out = (const float*)d_in[16];
  const float* b_out = (const float*)d_in[17];

  char* ws = (char*)d_ws;
  size_t off = 0;
  auto alloc = [&](size_t bytes) -> void* {
    void* p = ws + off;
    off = (off + bytes + 255) & ~(size_t)255;
    return p;
  };

  P_t P;
  P.x = x; P.noise = noise; P.b_cin = b_cin; P.b1 = b1; P.b2 = b2; P.b3 = b3;
  P.w4 = w4; P.b4 = b4; P.b_ih = b_ih; P.b_hh = b_hh; P.w_out = w_out; P.b_out = b_out;
  P.WT1    = (_Float16*)alloc((size_t)HH2 * HH2 * 2);
  P.WT2    = (_Float16*)alloc((size_t)HH2 * HH2 * 2);
  P.WT3    = (_Float16*)alloc((size_t)HH2 * HH2 * 2);
  P.WTih   = (_Float16*)alloc((size_t)GG3 * HSZ * 2);
  P.WThh   = (_Float16*)alloc((size_t)GG3 * HSZ * 2);
  P.WTcin  = (_Float16*)alloc((size_t)HSZ * DIN * 2);
  P.FW1T   = (_Float16*)alloc((size_t)HH2 * 512 * 2);
  P.FW1B   = (_Float16*)alloc((size_t)HH2 * 512 * 2);
  P.FW2    = (_Float16*)alloc((size_t)HH2 * HH2 * 2);
  P.FW3    = (_Float16*)alloc((size_t)HH2 * HH2 * 2);
  P.FWih   = (_Float16*)alloc((size_t)GG3 * HSZ * 2);
  P.FWhh   = (_Float16*)alloc((size_t)GG3 * HSZ * 2);
  P.CIN    = (_Float16*)alloc((size_t)SLEN * BSZ * HSZ * 2);
  P.Z1     = (_Float16*)alloc((size_t)BSZ * HH2 * 2);
  P.Z2     = (_Float16*)alloc((size_t)BSZ * HH2 * 2);
  P.HGRU16 = (_Float16*)alloc((size_t)BSZ * HSZ * 2);
  P.LOGI   = (float*)alloc((size_t)SLEN * BSZ * 4);
  P.C1     = (float*)alloc((size_t)BSZ * HH2 * 4);
  P.D1     = (float*)alloc((size_t)BSZ * HH2 * 4);
  P.CIH3   = (float*)alloc((size_t)BSZ * HSZ * 3 * 4);
  P.G3     = (float*)alloc((size_t)BSZ * HSZ * 3 * 4);
  P.A1     = (float*)alloc((size_t)BSZ * HH2 * 4);
  P.AIH3   = (float*)alloc((size_t)BSZ * HSZ * 3 * 4);
  P.AHH3   = (float*)alloc((size_t)BSZ * HSZ * 3 * 4);
  P.HF     = (float*)alloc((size_t)BSZ * HSZ * 4);
  P.HGRUF  = (float*)alloc((size_t)BSZ * HSZ * 4);
  P.NF     = (float*)alloc((size_t)2 * BSZ * 4);
  P.PART   = (float*)alloc((size_t)64 * BSZ * 4);
  P.CNT    = (int*)alloc(128 * 4);
  P.DEAD   = (int*)alloc(64 * 4);
  P.out    = (float*)d_out;

  transpose_cvt<<<(HH2/32)*(HH2/32), 256, 0, stream>>>(w1, P.WT1, HH2, HH2);
  transpose_cvt<<<(HH2/32)*(HH2/32), 256, 0, stream>>>(w2, P.WT2, HH2, HH2);
  transpose_cvt<<<(HH2/32)*(HH2/32), 256, 0, stream>>>(w3, P.WT3, HH2, HH2);
  transpose_cvt<<<(GG3/32)*(HSZ/32), 256, 0, stream>>>(w_ih, P.WTih, HSZ, GG3);
  transpose_cvt<<<(GG3/32)*(HSZ/32), 256, 0, stream>>>(w_hh, P.WThh, HSZ, GG3);
  transpose_cvt<<<(HSZ/32)*(DIN/32), 256, 0, stream>>>(w_cin, P.WTcin, DIN, HSZ);
  fragpack2<<<HH2/16, 512, 0, stream>>>(P.WT1, P.FW1T, HH2, 0, 512);
  fragpack2<<<HH2/16, 512, 0, stream>>>(P.WT1, P.FW1B, HH2, 512, 512);
  fragpack2<<<HH2/16, 512, 0, stream>>>(P.WT2, P.FW2, HH2, 0, HH2);
  fragpack2<<<HH2/16, 512, 0, stream>>>(P.WT3, P.FW3, HH2, 0, HH2);
  fragpack2<<<GG3/16, 512, 0, stream>>>(P.WTih, P.FWih, HSZ, 0, HSZ);
  fragpack2<<<GG3/16, 512, 0, stream>>>(P.WThh, P.FWhh, HSZ, 0, HSZ);

  cin_kernel<<<1024, 256, 0, stream>>>(P);
  init_kernel<<<256, 256, 0, stream>>>(P);
  boot_kernel<<<128, 256, 0, stream>>>(P);

  for (int t = 0; t < SLEN; ++t) {
    node_a<<<768, 64, 0, stream>>>(P, t);
    node_b<<<256, 256, 0, stream>>>(P, t);
  }
  final_out<<<BSZ, 256, 0, stream>>>(P);
}

// Round 11
// 6188.449 us; speedup vs baseline: 1.1766x; 1.1501x over previous
//
#include <hip/hip_runtime.h>
#include <math.h>

// Problem dims
#define SLEN 256
#define BSZ  128
#define DIN  128
#define HSZ  512
#define HH2  1024
#define GG3  1536
#define OSZ  25
#define SPIN_LIMIT (1 << 18)

typedef _Float16 h8 __attribute__((ext_vector_type(8)));
typedef _Float16 h4v __attribute__((ext_vector_type(4)));
typedef float    f4 __attribute__((ext_vector_type(4)));

struct P_t {
  const float *x, *noise, *b_cin, *b1, *b2, *b3, *w4, *b4, *b_ih, *b_hh, *w_out, *b_out;
  _Float16 *WT1, *WT2, *WT3, *WTih, *WThh, *WTcin;       // row-major [N][K] (setup)
  _Float16 *FW1T, *FW1B, *FW2, *FW3, *FWih, *FWhh;       // fragment-major (hot path)
  _Float16 *CIN, *Z1, *Z2, *HGRU16;
  float *LOGI, *C1, *D1, *CIH, *G;
  float *A1, *AIH, *AHH, *HF, *HGRUF, *NF, *PART;
  int *CNT;
  float *out;
};

__device__ __forceinline__ f4 mfma16(h8 a, h8 b, f4 c) {
  return __builtin_amdgcn_mfma_f32_16x16x32_f16(a, b, c, 0, 0, 0);
}

// div/mod by 24 via multiply-shift (u < 256)
__device__ __forceinline__ void div24(int u, int& quo, int& rem) {
  quo = (u * 0xAB) >> 12;          // floor(u/24) exact for u < 1536
  rem = u - quo * 24;
}

// ---- L3-coherent ops: ONLY for in-kernel cross-block data (PART, CNT) ----
__device__ __forceinline__ float ldc_f(const float* p) {
  return __hip_atomic_load(p, __ATOMIC_RELAXED, __HIP_MEMORY_SCOPE_AGENT);
}
__device__ __forceinline__ void stc_f(float* p, float v) {
  __hip_atomic_store(p, v, __ATOMIC_RELAXED, __HIP_MEMORY_SCOPE_AGENT);
}

// ---------------- setup kernels (proven) ----------------
__global__ __launch_bounds__(256) void transpose_cvt(const float* __restrict__ src,
    _Float16* __restrict__ dst, int K, int N) {
  __shared__ float tl[32][33];
  int nt = N >> 5;
  int bx = blockIdx.x % nt, by = blockIdx.x / nt;
  int n0 = bx << 5, k0 = by << 5;
  int tx = threadIdx.x & 31, ty = threadIdx.x >> 5;
#pragma unroll
  for (int i = 0; i < 4; ++i) {
    int r = ty + (i << 3);
    tl[r][tx] = src[(size_t)(k0 + r) * N + n0 + tx];
  }
  __syncthreads();
#pragma unroll
  for (int i = 0; i < 4; ++i) {
    int r = ty + (i << 3);
    dst[(size_t)(n0 + r) * K + k0 + tx] = (_Float16)tl[tx][r];
  }
}

__global__ __launch_bounds__(512) void fragpack2(const _Float16* __restrict__ src,
    _Float16* __restrict__ dst, int srcK, int kOff, int K) {
  int ct = blockIdx.x;
  int chunks = (K / 32) * 64;
  for (int idx = threadIdx.x; idx < chunks; idx += 512) {
    int i = idx >> 6, lane = idx & 63;
    int mlw = lane & 15, qw = lane >> 4;
    *(h8*)(dst + ((size_t)ct * (K / 32) + i) * 512 + (size_t)lane * 8) =
        *(const h8*)(src + ((size_t)ct * 16 + mlw) * srcK + kOff + i * 32 + qw * 8);
  }
}

__global__ __launch_bounds__(256) void cin_kernel(P_t P) {
  int tid = blockIdx.x * blockDim.x + threadIdx.x;
  if (tid < SLEN * BSZ) {
    float u = P.noise[tid];
    P.LOGI[tid] = logf(u) - log1pf(-u);
  }
  int gw = tid >> 6, lane = tid & 63;
  int nw = (gridDim.x * blockDim.x) >> 6;
  int ml = lane & 15, q = lane >> 4;
  const int MT = (SLEN * BSZ) / 16;
  for (int tt = gw; tt < MT * 8; tt += nw) {
    int mt = tt & (MT - 1), nt = tt / MT;
    int m0 = mt * 16, n0 = nt * 64;
    int m = m0 + ml, b = m & 127, s = m >> 7;
    const float* ap = P.x + ((size_t)b * SLEN + s) * DIN + q * 8;
    const _Float16* bp = P.WTcin + (size_t)(n0 + ml) * DIN + q * 8;
    f4 a0 = {0,0,0,0}, a1 = a0, a2 = a0, a3 = a0;
#pragma unroll
    for (int k = 0; k < DIN; k += 32) {
      f4 lo = *(const f4*)(ap + k);
      f4 hi = *(const f4*)(ap + k + 4);
      h8 av;
      av[0] = (_Float16)lo[0]; av[1] = (_Float16)lo[1];
      av[2] = (_Float16)lo[2]; av[3] = (_Float16)lo[3];
      av[4] = (_Float16)hi[0]; av[5] = (_Float16)hi[1];
      av[6] = (_Float16)hi[2]; av[7] = (_Float16)hi[3];
      a0 = mfma16(av, *(const h8*)(bp + k),            a0);
      a1 = mfma16(av, *(const h8*)(bp + 16*DIN + k),   a1);
      a2 = mfma16(av, *(const h8*)(bp + 32*DIN + k),   a2);
      a3 = mfma16(av, *(const h8*)(bp + 48*DIN + k),   a3);
    }
#pragma unroll
    for (int r = 0; r < 4; ++r) {
      int row = m0 + q * 4 + r;
      int c0 = n0 + ml;
      P.CIN[(size_t)row * HSZ + c0     ] = (_Float16)tanhf(a0[r] + P.b_cin[c0]);
      P.CIN[(size_t)row * HSZ + c0 + 16] = (_Float16)tanhf(a1[r] + P.b_cin[c0 + 16]);
      P.CIN[(size_t)row * HSZ + c0 + 32] = (_Float16)tanhf(a2[r] + P.b_cin[c0 + 32]);
      P.CIN[(size_t)row * HSZ + c0 + 48] = (_Float16)tanhf(a3[r] + P.b_cin[c0 + 48]);
    }
  }
}

__global__ __launch_bounds__(256) void init_kernel(P_t P) {
  int idx = blockIdx.x * 256 + threadIdx.x;                 // 65536 threads
  for (int i = idx; i < BSZ * GG3; i += 65536) { P.AIH[i] = 0.f; P.AHH[i] = 0.f; }
  for (int i = idx; i < BSZ * HH2; i += 65536) P.A1[i] = 0.f;
  if (idx < BSZ * HSZ) P.HF[idx] = 0.f;
  if (idx < 2 * BSZ) P.NF[idx] = 0.f;
  if (idx < 128) P.CNT[idx] = 0;
}

// bootstrap: Z1(0) = relu(cin(0)@W1bot + b1); HGRU(0) from biases (c=h=0).
__global__ __launch_bounds__(256) void boot_kernel(P_t P) {
  const int tid = threadIdx.x, lane = tid & 63, wv = tid >> 6;
  const int ml = lane & 15, q = lane >> 4;
  const int g = blockIdx.x * 4 + wv;                         // grid 128 -> g<512
  {
    int rt = g & 7, ct = g >> 3, m0 = rt << 4, col = (ct << 4) + ml;
    const _Float16* a0 = P.CIN + (size_t)(m0 + ml) * HSZ + q * 8;
    const _Float16* bp = P.FW1B + (size_t)ct * 16 * 512 + (size_t)lane * 8;
    f4 acc = {0.f, 0.f, 0.f, 0.f};
#pragma unroll
    for (int k = 0; k < 16; ++k)
      acc = mfma16(*(const h8*)(a0 + k * 32), *(const h8*)(bp + (size_t)k * 512), acc);
    float bia = P.b1[col];
#pragma unroll
    for (int j = 0; j < 4; ++j)
      P.Z1[(size_t)(m0 + q * 4 + j) * HH2 + col] = (_Float16)fmaxf(acc[j] + bia, 0.f);
  }
  int e = blockIdx.x * 512 + tid;
#pragma unroll
  for (int rep = 0; rep < 2; ++rep, e += 256) {
    int row = e >> 9, cc = e & 511;
    float rg = 1.f / (1.f + expf(-(P.b_ih[cc] + P.b_hh[cc])));
    float zg = 1.f / (1.f + expf(-(P.b_ih[cc + 512] + P.b_hh[cc + 512])));
    float ng = tanhf(P.b_ih[cc + 1024] + rg * P.b_hh[cc + 1024]);
    float v = (1.f - zg) * ng;
    P.HGRUF[(size_t)row * HSZ + cc] = v;
    P.HGRU16[(size_t)row * HSZ + cc] = (_Float16)v;
  }
}

// ---------------- node_a: independent GEMM bundle (XCD-local weight map) ----------------
// 768 blocks x 256 thr. Blocks sharing a weight tile ct are spaced by 16 or 24 in
// blockIdx (both ==0 mod 8) -> same XCD class -> each weight panel is fetched L3->L2
// ONCE per XCD per step instead of 8x. Section bases 128/320/448/640 all ==0 mod 8.
// Tiles (per block, 4 waves): z2 b<128 | G [128,320) | C1 [320,448) | CIH [448,640) | D1 [640,768)
__global__ __launch_bounds__(256) void node_a(P_t P, int t) {
  const int tid = threadIdx.x, lane = tid & 63, wv = tid >> 6;
  const int ml = lane & 15, q = lane >> 4;
  const int b = blockIdx.x;
  f4 acc = {0.f, 0.f, 0.f, 0.f};
  if (b < 128) {                       // z2 (K=1024): rt=b>>4, ct=(b&15)*4+wv
    int rt = b >> 4, ct = (b & 15) * 4 + wv;
    int m0 = rt << 4, col = (ct << 4) + ml;
    const _Float16* a0 = P.Z1 + (size_t)(m0 + ml) * HH2 + q * 8;
    const _Float16* bp = P.FW2 + (size_t)ct * 32 * 512 + (size_t)lane * 8;
#pragma unroll
    for (int k = 0; k < 32; ++k)
      acc = mfma16(*(const h8*)(a0 + k * 32), *(const h8*)(bp + (size_t)k * 512), acc);
    float bia = P.b2[col];
#pragma unroll
    for (int j = 0; j < 4; ++j)
      P.Z2[(size_t)(m0 + q * 4 + j) * HH2 + col] = (_Float16)fmaxf(acc[j] + bia, 0.f);
  } else if (b < 320) {                // G = HGRU16 @ Whh: u=rt*24+bb, ct=bb*4+wv
    int u = b - 128, rt, bb; div24(u, rt, bb);
    int ct = bb * 4 + wv;
    int m0 = rt << 4, col = (ct << 4) + ml;
    const _Float16* a0 = P.HGRU16 + (size_t)(m0 + ml) * HSZ + q * 8;
    const _Float16* bp = P.FWhh + (size_t)ct * 16 * 512 + (size_t)lane * 8;
#pragma unroll
    for (int k = 0; k < 16; ++k)
      acc = mfma16(*(const h8*)(a0 + k * 32), *(const h8*)(bp + (size_t)k * 512), acc);
#pragma unroll
    for (int j = 0; j < 4; ++j)
      P.G[(size_t)(m0 + q * 4 + j) * GG3 + col] = acc[j];
  } else if (b < 448) {                // C1 = cin(t) @ W1top: u=rt*16+bb
    int u = b - 320, rt = u >> 4, ct = (u & 15) * 4 + wv;
    int m0 = rt << 4, col = (ct << 4) + ml;
    const _Float16* a0 = P.CIN + ((size_t)t * BSZ + m0 + ml) * HSZ + q * 8;
    const _Float16* bp = P.FW1T + (size_t)ct * 16 * 512 + (size_t)lane * 8;
#pragma unroll
    for (int k = 0; k < 16; ++k)
      acc = mfma16(*(const h8*)(a0 + k * 32), *(const h8*)(bp + (size_t)k * 512), acc);
#pragma unroll
    for (int j = 0; j < 4; ++j)
      P.C1[(size_t)(m0 + q * 4 + j) * HH2 + col] = acc[j];
  } else if (b < 640) {                // CIH = cin(t) @ Wih: u=rt*24+bb
    int u = b - 448, rt, bb; div24(u, rt, bb);
    int ct = bb * 4 + wv;
    int m0 = rt << 4, col = (ct << 4) + ml;
    const _Float16* a0 = P.CIN + ((size_t)t * BSZ + m0 + ml) * HSZ + q * 8;
    const _Float16* bp = P.FWih + (size_t)ct * 16 * 512 + (size_t)lane * 8;
#pragma unroll
    for (int k = 0; k < 16; ++k)
      acc = mfma16(*(const h8*)(a0 + k * 32), *(const h8*)(bp + (size_t)k * 512), acc);
#pragma unroll
    for (int j = 0; j < 4; ++j)
      P.CIH[(size_t)(m0 + q * 4 + j) * GG3 + col] = acc[j];
  } else {                             // D1 = cin(t+1) @ W1bot: u=rt*16+bb
    if (t + 1 < SLEN) {
      int u = b - 640, rt = u >> 4, ct = (u & 15) * 4 + wv;
      int m0 = rt << 4, col = (ct << 4) + ml;
      const _Float16* a0 = P.CIN + ((size_t)(t + 1) * BSZ + m0 + ml) * HSZ + q * 8;
      const _Float16* bp = P.FW1B + (size_t)ct * 16 * 512 + (size_t)lane * 8;
#pragma unroll
      for (int k = 0; k < 16; ++k)
        acc = mfma16(*(const h8*)(a0 + k * 32), *(const h8*)(bp + (size_t)k * 512), acc);
#pragma unroll
      for (int j = 0; j < 4; ++j)
        P.D1[(size_t)(m0 + q * 4 + j) * HH2 + col] = acc[j];
    }
  }
}

// ---------------- node_b: z3 -> PART (L3) -> per-rt barrier -> tail ----------------
// 128 blocks x 256 thr. rt = b>>4, sub = b&15 so the 8 row-peers of each FW3 tile
// share blockIdx%8 -> same XCD -> FW3 fetched once/XCD. Otherwise identical to the
// 6443us R7 version.
__global__ __launch_bounds__(256) void node_b(P_t P, int t) {
  const int tid = threadIdx.x, lane = tid & 63, wv = tid >> 6;
  const int ml = lane & 15, q = lane >> 4;
  const int b = blockIdx.x, rt = b >> 4, sub = b & 15;
  const int m0 = rt << 4;
  __shared__ float sAl[16], sNN[16];

  // z3 tile -> PART
  {
    int ct = sub * 4 + wv, col = (ct << 4) + ml;
    const _Float16* a0 = P.Z2 + (size_t)(m0 + ml) * HH2 + q * 8;
    const _Float16* bp = P.FW3 + (size_t)ct * 32 * 512 + (size_t)lane * 8;
    f4 acc = {0.f, 0.f, 0.f, 0.f};
#pragma unroll
    for (int k = 0; k < 32; ++k)
      acc = mfma16(*(const h8*)(a0 + k * 32), *(const h8*)(bp + (size_t)k * 512), acc);
    float bia = P.b3[col], w4v = P.w4[col];
#pragma unroll
    for (int j = 0; j < 4; ++j) {
      float v = fmaxf(acc[j] + bia, 0.f) * w4v;
      v += __shfl_xor(v, 1); v += __shfl_xor(v, 2);
      v += __shfl_xor(v, 4); v += __shfl_xor(v, 8);
      if (ml == 0) stc_f(&P.PART[(size_t)ct * BSZ + m0 + q * 4 + j], v);
    }
  }
  asm volatile("s_waitcnt vmcnt(0)" ::: "memory");
  __syncthreads();
  if (tid == 0) {
    __hip_atomic_fetch_add(&P.CNT[rt * 16], 1, __ATOMIC_RELAXED, __HIP_MEMORY_SCOPE_AGENT);
    const int target = 16 * (t + 1);
    int tries = 0;
    while (__hip_atomic_load(&P.CNT[rt * 16], __ATOMIC_RELAXED,
                             __HIP_MEMORY_SCOPE_AGENT) < target) {
      if (++tries > SPIN_LIMIT) break;      // graceful: wrong answer, never hang
      __builtin_amdgcn_s_sleep(1);
    }
  }
  __syncthreads();

  // alpha(t), n(t)
  {
    int rl = tid >> 4, sg = tid & 15, row = m0 + rl;
    float v = 0.f;
#pragma unroll
    for (int k2 = 0; k2 < 4; ++k2)
      v += ldc_f(&P.PART[(size_t)(sg * 4 + k2) * BSZ + row]);
    v += __shfl_xor(v, 1); v += __shfl_xor(v, 2);
    v += __shfl_xor(v, 4); v += __shfl_xor(v, 8);
    if (sg == 0) {
      float lg = (v + P.b4[0] + P.LOGI[(size_t)t * BSZ + row]) * 10.0f;
      float al = 1.f / (1.f + expf(-lg));
      float no = P.NF[((t + 1) & 1) * BSZ + row];
      float nn = no * (1.f - al) + 1.f;
      sAl[rl] = al; sNN[rl] = nn;
      if (sub == 0) P.NF[(t & 1) * BSZ + row] = nn;
    }
  }
  __syncthreads();

  // A1 slice (16 rows x 64 cols) + Z1(t+1)
  {
    int rl = tid >> 4, row = m0 + rl;
    int c0 = sub * 64 + (tid & 15) * 4;
    float al = sAl[rl], om = 1.f - al, rin = 1.f / sNN[rl];
    size_t o = (size_t)row * HH2 + c0;
    f4 a = *(f4*)(P.A1 + o);
    f4 c1 = *(const f4*)(P.C1 + o);
#pragma unroll
    for (int j = 0; j < 4; ++j) a[j] = om * a[j] + c1[j];
    *(f4*)(P.A1 + o) = a;
    if (t + 1 < SLEN) {
      f4 d = *(const f4*)(P.D1 + o);
      f4 bb = *(const f4*)(P.b1 + c0);
      h4v zo;
#pragma unroll
      for (int j = 0; j < 4; ++j)
        zo[j] = (_Float16)fmaxf(a[j] * rin + d[j] + bb[j], 0.f);
      *(h4v*)(P.Z1 + o) = zo;
    }
  }

  // AIH/AHH/gates/h/HGRU slice (16 rows x 32 h-cols, gate triples)
  {
    int rl = tid >> 4, row = m0 + rl;
    float al = sAl[rl], om = 1.f - al, rin = 1.f / sNN[rl];
    int cbase = sub * 32 + (tid & 15) * 2;
#pragma unroll
    for (int e = 0; e < 2; ++e) {
      int cc = cbase + e;
      size_t o3 = (size_t)row * GG3 + cc;
      float air = om * P.AIH[o3]        + P.CIH[o3];
      float aiz = om * P.AIH[o3 + 512]  + P.CIH[o3 + 512];
      float ain = om * P.AIH[o3 + 1024] + P.CIH[o3 + 1024];
      P.AIH[o3] = air; P.AIH[o3 + 512] = aiz; P.AIH[o3 + 1024] = ain;
      float ahr = om * P.AHH[o3]        + al * P.G[o3];
      float ahz = om * P.AHH[o3 + 512]  + al * P.G[o3 + 512];
      float ahn = om * P.AHH[o3 + 1024] + al * P.G[o3 + 1024];
      P.AHH[o3] = ahr; P.AHH[o3 + 512] = ahz; P.AHH[o3 + 1024] = ahn;
      float gxr = air * rin + P.b_ih[cc];
      float gxz = aiz * rin + P.b_ih[cc + 512];
      float gxn = ain * rin + P.b_ih[cc + 1024];
      float ghr = ahr + P.b_hh[cc];
      float ghz = ahz + P.b_hh[cc + 512];
      float ghn = ahn + P.b_hh[cc + 1024];
      float rg = 1.f / (1.f + expf(-(gxr + ghr)));
      float zg = 1.f / (1.f + expf(-(gxz + ghz)));
      float ng = tanhf(gxn + rg * ghn);
      size_t oh = (size_t)row * HSZ + cc;
      float hold = P.HF[oh];
      float hgt  = P.HGRUF[oh];             // HGRU(t)
      float hnew = om * hold + al * hgt;    // h(t)
      P.HF[oh] = hnew;
      float hg1 = (1.f - zg) * ng + zg * hnew;   // HGRU(t+1) = gru_cell(c(t),h(t))
      P.HGRUF[oh] = hg1;
      P.HGRU16[oh] = (_Float16)hg1;
    }
  }
}

// ---------------- final: out = HGRU(256) @ w_out + b_out ----------------
__global__ __launch_bounds__(256) void final_out(P_t P) {
  __shared__ float hf[512];
  const int r = blockIdx.x, tid = threadIdx.x;
  const int lane = tid & 63, wv = tid >> 6;
  for (int e = tid; e < 512; e += 256) hf[e] = P.HGRUF[(size_t)r * HSZ + e];
  __syncthreads();
  for (int c = wv; c < OSZ; c += 4) {
    float v = 0.f;
#pragma unroll
    for (int j = 0; j < 8; ++j)
      v += hf[lane + 64 * j] * P.w_out[(size_t)(lane + 64 * j) * OSZ + c];
    for (int off = 32; off > 0; off >>= 1) v += __shfl_xor(v, off);
    if (lane == 0) P.out[r * OSZ + c] = v + P.b_out[c];
  }
}

// ---------------- host ----------------
extern "C" void kernel_launch(void* const* d_in, const int* in_sizes, int n_in,
                              void* d_out, int out_size, void* d_ws, size_t ws_size,
                              hipStream_t stream) {
  const float* x     = (const float*)d_in[0];
  const float* noise = (const float*)d_in[1];
  const float* w_cin = (const float*)d_in[2];
  const float* b_cin = (const float*)d_in[3];
  const float* w1    = (const float*)d_in[4];
  const float* b1    = (const float*)d_in[5];
  const float* w2    = (const float*)d_in[6];
  const float* b2    = (const float*)d_in[7];
  const float* w3    = (const float*)d_in[8];
  const float* b3    = (const float*)d_in[9];
  const float* w4    = (const float*)d_in[10];
  const float* b4    = (const float*)d_in[11];
  const float* w_ih  = (const float*)d_in[12];
  const float* b_ih  = (const float*)d_in[13];
  const float* w_hh  = (const float*)d_in[14];
  const float* b_hh  = (const float*)d_in[15];
  const float* w_out = (const float*)d_in[16];
  const float* b_out = (const float*)d_in[17];

  char* ws = (char*)d_ws;
  size_t off = 0;
  auto alloc = [&](size_t bytes) -> void* {
    void* p = ws + off;
    off = (off + bytes + 255) & ~(size_t)255;
    return p;
  };

  P_t P;
  P.x = x; P.noise = noise; P.b_cin = b_cin; P.b1 = b1; P.b2 = b2; P.b3 = b3;
  P.w4 = w4; P.b4 = b4; P.b_ih = b_ih; P.b_hh = b_hh; P.w_out = w_out; P.b_out = b_out;
  P.WT1    = (_Float16*)alloc((size_t)HH2 * HH2 * 2);
  P.WT2    = (_Float16*)alloc((size_t)HH2 * HH2 * 2);
  P.WT3    = (_Float16*)alloc((size_t)HH2 * HH2 * 2);
  P.WTih   = (_Float16*)alloc((size_t)GG3 * HSZ * 2);
  P.WThh   = (_Float16*)alloc((size_t)GG3 * HSZ * 2);
  P.WTcin  = (_Float16*)alloc((size_t)HSZ * DIN * 2);
  P.FW1T   = (_Float16*)alloc((size_t)HH2 * 512 * 2);
  P.FW1B   = (_Float16*)alloc((size_t)HH2 * 512 * 2);
  P.FW2    = (_Float16*)alloc((size_t)HH2 * HH2 * 2);
  P.FW3    = (_Float16*)alloc((size_t)HH2 * HH2 * 2);
  P.FWih   = (_Float16*)alloc((size_t)GG3 * HSZ * 2);
  P.FWhh   = (_Float16*)alloc((size_t)GG3 * HSZ * 2);
  P.CIN    = (_Float16*)alloc((size_t)SLEN * BSZ * HSZ * 2);
  P.Z1     = (_Float16*)alloc((size_t)BSZ * HH2 * 2);
  P.Z2     = (_Float16*)alloc((size_t)BSZ * HH2 * 2);
  P.HGRU16 = (_Float16*)alloc((size_t)BSZ * HSZ * 2);
  P.LOGI   = (float*)alloc((size_t)SLEN * BSZ * 4);
  P.C1     = (float*)alloc((size_t)BSZ * HH2 * 4);
  P.D1     = (float*)alloc((size_t)BSZ * HH2 * 4);
  P.CIH    = (float*)alloc((size_t)BSZ * GG3 * 4);
  P.G      = (float*)alloc((size_t)BSZ * GG3 * 4);
  P.A1     = (float*)alloc((size_t)BSZ * HH2 * 4);
  P.AIH    = (float*)alloc((size_t)BSZ * GG3 * 4);
  P.AHH    = (float*)alloc((size_t)BSZ * GG3 * 4);
  P.HF     = (float*)alloc((size_t)BSZ * HSZ * 4);
  P.HGRUF  = (float*)alloc((size_t)BSZ * HSZ * 4);
  P.NF     = (float*)alloc((size_t)2 * BSZ * 4);
  P.PART   = (float*)alloc((size_t)64 * BSZ * 4);
  P.CNT    = (int*)alloc(128 * 4);
  P.out    = (float*)d_out;

  transpose_cvt<<<(HH2/32)*(HH2/32), 256, 0, stream>>>(w1, P.WT1, HH2, HH2);
  transpose_cvt<<<(HH2/32)*(HH2/32), 256, 0, stream>>>(w2, P.WT2, HH2, HH2);
  transpose_cvt<<<(HH2/32)*(HH2/32), 256, 0, stream>>>(w3, P.WT3, HH2, HH2);
  transpose_cvt<<<(GG3/32)*(HSZ/32), 256, 0, stream>>>(w_ih, P.WTih, HSZ, GG3);
  transpose_cvt<<<(GG3/32)*(HSZ/32), 256, 0, stream>>>(w_hh, P.WThh, HSZ, GG3);
  transpose_cvt<<<(HSZ/32)*(DIN/32), 256, 0, stream>>>(w_cin, P.WTcin, DIN, HSZ);
  fragpack2<<<HH2/16, 512, 0, stream>>>(P.WT1, P.FW1T, HH2, 0, 512);
  fragpack2<<<HH2/16, 512, 0, stream>>>(P.WT1, P.FW1B, HH2, 512, 512);
  fragpack2<<<HH2/16, 512, 0, stream>>>(P.WT2, P.FW2, HH2, 0, HH2);
  fragpack2<<<HH2/16, 512, 0, stream>>>(P.WT3, P.FW3, HH2, 0, HH2);
  fragpack2<<<GG3/16, 512, 0, stream>>>(P.WTih, P.FWih, HSZ, 0, HSZ);
  fragpack2<<<GG3/16, 512, 0, stream>>>(P.WThh, P.FWhh, HSZ, 0, HSZ);

  cin_kernel<<<1024, 256, 0, stream>>>(P);
  init_kernel<<<256, 256, 0, stream>>>(P);
  boot_kernel<<<128, 256, 0, stream>>>(P);

  for (int t = 0; t < SLEN; ++t) {
    node_a<<<768, 256, 0, stream>>>(P, t);
    node_b<<<128, 256, 0, stream>>>(P, t);
  }
  final_out<<<BSZ, 256, 0, stream>>>(P);
}